// Round 14
// baseline (45.535 us; speedup 1.0000x reference)
//
#include <hip/hip_runtime.h>

#define B 4
#define N 1024
#define K 100
#define F 42
#define H 64

#define PAIRS (K * F)          // 4200
#define MF4   (PAIRS * 3 / 4)  // 3150 f32x4 of dfeat per atom
#define QP    (PAIRS / 4)      // 1050 quad-pairs per atom

#define APW 2                  // mlp: atoms per wave
#define NWV 8                  // mlp: waves per block -> 2 waves/SIMD
#define APB (APW * NWV)        // 16 atoms/block -> grid 256
#define BT  (NWV * 64)         // 512 threads
#define PW  68                 // row pad: (4*lane)%32 start-bank spread for b128

typedef float f32x4 __attribute__((ext_vector_type(4)));

__device__ __forceinline__ float rl(float v, int l) {
    return __int_as_float(__builtin_amdgcn_readlane(__float_as_int(v), l));
}

// ---------------------------------------------------------------------------
// Kernel 1 (v14): MLP fwd + input grad. lane = hidden unit, wave = 2 atoms,
// 8 waves/block, grid 256.
//  - W in LDS, DUAL LAYOUT: W1T/W2T (transposed -> forward column = per-lane
//    contiguous row, b128) and W1s/W2s (row-major -> backward row, b128).
//    59 x ds_read_b128 per wave total; zero b32 W reads.
//  - ALL activation broadcasts via v_readlane (VALU), no LDS exchanges at all.
//    readlane only under full exec (v11 lesson); 4-way split accumulators.
// ---------------------------------------------------------------------------
__global__ __launch_bounds__(BT) void mlp_kernel(
    const float* __restrict__ image,
    const float* __restrict__ W1, const float* __restrict__ b1,
    const float* __restrict__ W2, const float* __restrict__ b2,
    const float* __restrict__ W3, const float* __restrict__ b3,
    float* __restrict__ Ei, float* __restrict__ dE)
{
    __shared__ __align__(16) float W1T[H][PW];   // W1T[i][f] = W1[f][i]; f>=F zeroed
    __shared__ __align__(16) float W2T[H][PW];   // W2T[i][j] = W2[j][i]
    __shared__ __align__(16) float W1s[H][PW];   // W1[f][i]; rows f>=F zeroed
    __shared__ __align__(16) float W2s[H][PW];   // W2[j][i]

    const int tid  = threadIdx.x;
    const int lane = tid & 63;
    const int wv   = tid >> 6;
    const int aw   = blockIdx.x * APB + wv * APW;

    // zero-init transposed/padded regions that matter, then scatter/copy
    for (int idx = tid; idx < H * PW; idx += BT) {
        ((float*)W1T)[idx] = 0.0f;
        ((float*)W1s)[idx] = 0.0f;
    }
    __syncthreads();
    for (int idx = tid; idx < F * H; idx += BT) {
        const int r = idx >> 6, c = idx & 63;    // W1[r][c]
        W1s[r][c] = W1[idx];
        W1T[c][r] = W1[idx];
    }
    for (int idx = tid; idx < H * H; idx += BT) {
        const int r = idx >> 6, c = idx & 63;    // W2[r][c]
        W2s[r][c] = W2[idx];
        W2T[c][r] = W2[idx];
    }
    __syncthreads();

    // x: lane f holds image[atom][f] (0 for f >= F)
    float x[APW];
    #pragma unroll
    for (int a = 0; a < APW; ++a)
        x[a] = (lane < F) ? image[(size_t)(aw + a) * F + lane] : 0.0f;

    // ---- layer 1: acc[a] = b1[lane] + sum_f x[a][f] * W1[f][lane] ----
    float p[APW][4];
    #pragma unroll
    for (int a = 0; a < APW; ++a)
        #pragma unroll
        for (int t = 0; t < 4; ++t) p[a][t] = 0.0f;
    #pragma unroll
    for (int fc = 0; fc < 11; ++fc) {            // f = 0..43 (42,43 are zeros)
        const f32x4 w = *(const f32x4*)&W1T[lane][4 * fc];
        #pragma unroll
        for (int a = 0; a < APW; ++a) {
            p[a][0] = fmaf(rl(x[a], 4 * fc + 0), w.x, p[a][0]);
            p[a][1] = fmaf(rl(x[a], 4 * fc + 1), w.y, p[a][1]);
            p[a][2] = fmaf(rl(x[a], 4 * fc + 2), w.z, p[a][2]);
            p[a][3] = fmaf(rl(x[a], 4 * fc + 3), w.w, p[a][3]);
        }
    }
    const float bb1 = b1[lane];
    float h1l[APW];
    #pragma unroll
    for (int a = 0; a < APW; ++a)
        h1l[a] = tanhf((p[a][0] + p[a][1]) + (p[a][2] + p[a][3]) + bb1);

    // ---- layer 2: b2[lane] + sum_j h1[a][j] * W2[j][lane] ----
    #pragma unroll
    for (int a = 0; a < APW; ++a)
        #pragma unroll
        for (int t = 0; t < 4; ++t) p[a][t] = 0.0f;
    #pragma unroll
    for (int jc = 0; jc < H / 4; ++jc) {
        const f32x4 w = *(const f32x4*)&W2T[lane][4 * jc];
        #pragma unroll
        for (int a = 0; a < APW; ++a) {
            p[a][0] = fmaf(rl(h1l[a], 4 * jc + 0), w.x, p[a][0]);
            p[a][1] = fmaf(rl(h1l[a], 4 * jc + 1), w.y, p[a][1]);
            p[a][2] = fmaf(rl(h1l[a], 4 * jc + 2), w.z, p[a][2]);
            p[a][3] = fmaf(rl(h1l[a], 4 * jc + 3), w.w, p[a][3]);
        }
    }
    const float bb2   = b2[lane];
    const float w3    = W3[lane];
    const float bias3 = b3[0];
    float g2l[APW];
    #pragma unroll
    for (int a = 0; a < APW; ++a) {
        const float h2 = tanhf((p[a][0] + p[a][1]) + (p[a][2] + p[a][3]) + bb2);
        g2l[a] = w3 * (1.0f - h2 * h2);
        float t = h2 * w3;
        #pragma unroll
        for (int off = 32; off > 0; off >>= 1) t += __shfl_down(t, off);
        if (lane == 0) Ei[aw + a] = t + bias3;
    }

    // ---- g1[lane] = (1-h1^2) * sum_i W2[lane][i] * g2[i] ----
    #pragma unroll
    for (int a = 0; a < APW; ++a)
        #pragma unroll
        for (int t = 0; t < 4; ++t) p[a][t] = 0.0f;
    #pragma unroll
    for (int ic = 0; ic < H / 4; ++ic) {
        const f32x4 w = *(const f32x4*)&W2s[lane][4 * ic];
        #pragma unroll
        for (int a = 0; a < APW; ++a) {
            p[a][0] = fmaf(rl(g2l[a], 4 * ic + 0), w.x, p[a][0]);
            p[a][1] = fmaf(rl(g2l[a], 4 * ic + 1), w.y, p[a][1]);
            p[a][2] = fmaf(rl(g2l[a], 4 * ic + 2), w.z, p[a][2]);
            p[a][3] = fmaf(rl(g2l[a], 4 * ic + 3), w.w, p[a][3]);
        }
    }
    float g1l[APW];
    #pragma unroll
    for (int a = 0; a < APW; ++a)
        g1l[a] = ((p[a][0] + p[a][1]) + (p[a][2] + p[a][3])) * (1.0f - h1l[a] * h1l[a]);

    // ---- dx[f=lane] = sum_i W1[lane][i] * g1[i]  (full exec; W1s rows >= F
    //      are zero so lanes 42..63 compute benign zeros) ----
    #pragma unroll
    for (int a = 0; a < APW; ++a)
        #pragma unroll
        for (int t = 0; t < 4; ++t) p[a][t] = 0.0f;
    #pragma unroll
    for (int ic = 0; ic < H / 4; ++ic) {
        const f32x4 w = *(const f32x4*)&W1s[lane][4 * ic];
        #pragma unroll
        for (int a = 0; a < APW; ++a) {
            p[a][0] = fmaf(rl(g1l[a], 4 * ic + 0), w.x, p[a][0]);
            p[a][1] = fmaf(rl(g1l[a], 4 * ic + 1), w.y, p[a][1]);
            p[a][2] = fmaf(rl(g1l[a], 4 * ic + 2), w.z, p[a][2]);
            p[a][3] = fmaf(rl(g1l[a], 4 * ic + 3), w.w, p[a][3]);
        }
    }
    if (lane < F) {
        #pragma unroll
        for (int a = 0; a < APW; ++a)
            dE[(size_t)(aw + a) * F + lane] =
                (p[a][0] + p[a][1]) + (p[a][2] + p[a][3]);
    }
}

// ---------------------------------------------------------------------------
// Kernel 2 (R9, byte-identical — ~6.6 TB/s effective, at/above copy ceiling):
// Force with inline gather + dwordx4 dfeat stream, + Etot tail blocks.
// ---------------------------------------------------------------------------
__global__ __launch_bounds__(256) void force_kernel(
    const float* __restrict__ dE, const float* __restrict__ dfeat,
    const int* __restrict__ neighbor, const float* __restrict__ Ei,
    float* __restrict__ force, float* __restrict__ Etot)
{
    __shared__ int   nsh[K];
    __shared__ float red[4][3];

    const int tid  = threadIdx.x;
    const int bid  = blockIdx.x;
    const int lane = tid & 63, wave = tid >> 6;

    if (bid >= B * N) {                    // ---- Etot tail blocks ----
        const int b = bid - B * N;
        float s = 0.0f;
        for (int i = tid; i < N; i += 256) s += Ei[b * N + i];
        #pragma unroll
        for (int off = 32; off > 0; off >>= 1) s += __shfl_down(s, off);
        if (lane == 0) red[wave][0] = s;
        __syncthreads();
        if (tid == 0)
            Etot[b] = (red[0][0] + red[1][0]) + (red[2][0] + red[3][0]);
        return;
    }

    const int bn = bid;
    const int b  = bn >> 10;               // N = 1024

    if (tid < K) nsh[tid] = neighbor[bn * K + tid];
    __syncthreads();

    const f32x4* df4 = (const f32x4*)dfeat + (size_t)bn * MF4;
    const float* dEb = dE + (size_t)b * (N * F);

    float fx = 0.0f, fy = 0.0f, fz = 0.0f;

    #pragma unroll 1
    for (int it = 0; it < 4; ++it) {       // full iters: quad-pairs 0..1023
        const int p4 = it * 256 + tid;
        const int p  = 4 * p4;
        const f32x4 d0 = df4[3 * p4 + 0];
        const f32x4 d1 = df4[3 * p4 + 1];
        const f32x4 d2 = df4[3 * p4 + 2];
        float e[4];
        #pragma unroll
        for (int q = 0; q < 4; ++q) {
            const int pp = p + q;
            const int k  = pp / F;
            const int f  = pp - k * F;
            const int nb = nsh[k];
            e[q] = (nb > 0) ? dEb[(nb - 1) * F + f] : 0.0f;
        }
        fx = fmaf(e[0], d0.x, fx); fy = fmaf(e[0], d0.y, fy); fz = fmaf(e[0], d0.z, fz);
        fx = fmaf(e[1], d0.w, fx); fy = fmaf(e[1], d1.x, fy); fz = fmaf(e[1], d1.y, fz);
        fx = fmaf(e[2], d1.z, fx); fy = fmaf(e[2], d1.w, fy); fz = fmaf(e[2], d2.x, fz);
        fx = fmaf(e[3], d2.y, fx); fy = fmaf(e[3], d2.z, fy); fz = fmaf(e[3], d2.w, fz);
    }
    if (tid < QP - 1024) {                 // tail: quad-pairs 1024..1049
        const int p4 = 1024 + tid;
        const int p  = 4 * p4;
        const f32x4 d0 = df4[3 * p4 + 0];
        const f32x4 d1 = df4[3 * p4 + 1];
        const f32x4 d2 = df4[3 * p4 + 2];
        float e[4];
        #pragma unroll
        for (int q = 0; q < 4; ++q) {
            const int pp = p + q;
            const int k  = pp / F;
            const int f  = pp - k * F;
            const int nb = nsh[k];
            e[q] = (nb > 0) ? dEb[(nb - 1) * F + f] : 0.0f;
        }
        fx = fmaf(e[0], d0.x, fx); fy = fmaf(e[0], d0.y, fy); fz = fmaf(e[0], d0.z, fz);
        fx = fmaf(e[1], d0.w, fx); fy = fmaf(e[1], d1.x, fy); fz = fmaf(e[1], d1.y, fz);
        fx = fmaf(e[2], d1.z, fx); fy = fmaf(e[2], d1.w, fy); fz = fmaf(e[2], d2.x, fz);
        fx = fmaf(e[3], d2.y, fx); fy = fmaf(e[3], d2.z, fy); fz = fmaf(e[3], d2.w, fz);
    }

    #pragma unroll
    for (int off = 32; off > 0; off >>= 1) {
        fx += __shfl_down(fx, off);
        fy += __shfl_down(fy, off);
        fz += __shfl_down(fz, off);
    }
    if (lane == 0) { red[wave][0] = fx; red[wave][1] = fy; red[wave][2] = fz; }
    __syncthreads();
    if (tid == 0) {
        force[bn * 3 + 0] = (red[0][0] + red[1][0]) + (red[2][0] + red[3][0]);
        force[bn * 3 + 1] = (red[0][1] + red[1][1]) + (red[2][1] + red[3][1]);
        force[bn * 3 + 2] = (red[0][2] + red[1][2]) + (red[2][2] + red[3][2]);
    }
}

extern "C" void kernel_launch(void* const* d_in, const int* in_sizes, int n_in,
                              void* d_out, int out_size, void* d_ws, size_t ws_size,
                              hipStream_t stream)
{
    const float* image    = (const float*)d_in[0];
    const float* dfeat    = (const float*)d_in[1];
    const int*   neighbor = (const int*)d_in[2];
    // d_in[3] Egroup_weight, d_in[4] divider: unused by the reference outputs
    const float* W1 = (const float*)d_in[5];
    const float* b1 = (const float*)d_in[6];
    const float* W2 = (const float*)d_in[7];
    const float* b2 = (const float*)d_in[8];
    const float* W3 = (const float*)d_in[9];
    const float* b3 = (const float*)d_in[10];

    float* out   = (float*)d_out;
    float* Etot  = out;                 // [B]
    float* Ei    = out + B;             // [B,N]
    float* Force = out + B + B * N;     // [B,N,3]
    float* dE    = (float*)d_ws;        // [B,N,F]

    mlp_kernel<<<(B * N) / APB, BT, 0, stream>>>(image, W1, b1, W2, b2, W3, b3, Ei, dE);
    force_kernel<<<B * N + B, 256, 0, stream>>>(dE, dfeat, neighbor, Ei, Force, Etot);
}